// Round 12
// baseline (15.582 us; speedup 1.0000x reference)
//
#include <hip/hip_runtime.h>

constexpr int NW = 12;
constexpr int BT = 1024;  // 1 sample/block; storage idx = [j:2][W:4][l:6]
constexpr int NA = 4;     // amps per thread

typedef float f32x2 __attribute__((ext_vector_type(2)));
typedef float f32x4 __attribute__((ext_vector_type(4)));

// ---- packed FP32 complex math (HW-validated R8-R11) ----
__device__ __forceinline__ f32x2 pkmul(f32x2 a, f32x2 b) {
    f32x2 d; asm("v_pk_mul_f32 %0, %1, %2" : "=v"(d) : "v"(a), "v"(b)); return d;
}
__device__ __forceinline__ f32x2 pkfma(f32x2 a, f32x2 b, f32x2 c) {
    f32x2 d; asm("v_pk_fma_f32 %0, %1, %2, %3" : "=v"(d) : "v"(a), "v"(b), "v"(c)); return d;
}
__device__ __forceinline__ f32x2 pkfma_swapneg(f32x2 a, f32x2 b, f32x2 c) {
    f32x2 d;
    asm("v_pk_fma_f32 %0, %1, %2, %3 op_sel:[1,0,0] op_sel_hi:[0,1,1] neg_lo:[1,0,0]"
        : "=v"(d) : "v"(a), "v"(b), "v"(c));
    return d;
}
__device__ __forceinline__ f32x2 cmul(f32x2 z, f32x2 ur, f32x2 ui) {
    return pkfma_swapneg(z, ui, pkmul(z, ur));
}
__device__ __forceinline__ f32x2 cmac(f32x2 z, f32x2 ur, f32x2 ui, f32x2 acc) {
    return pkfma_swapneg(z, ui, pkfma(z, ur, acc));
}

struct St { f32x2 z[NA]; };

// ---- cross-lane partner across lane-xor M (validated R6) ----
template<int CTRL>
__device__ __forceinline__ float dppx(float v) {
    int r = __builtin_amdgcn_update_dpp(0, __builtin_bit_cast(int, v), CTRL, 0xF, 0xF, true);
    return __builtin_bit_cast(float, r);
}
template<int M>
__device__ __forceinline__ float lxor(float v, int bp32) {
    if constexpr (M == 1)      { return dppx<0xB1>(v); }
    else if constexpr (M == 2) { return dppx<0x4E>(v); }
    else if constexpr (M == 8) { return dppx<0x128>(v); }
    else if constexpr (M == 4) {
        int r = __builtin_amdgcn_ds_swizzle(__builtin_bit_cast(int, v), 0x101F);
        return __builtin_bit_cast(float, r);
    } else if constexpr (M == 16) {
        int r = __builtin_amdgcn_ds_swizzle(__builtin_bit_cast(int, v), 0x401F);
        return __builtin_bit_cast(float, r);
    } else {
        int r = __builtin_amdgcn_ds_bpermute(bp32, __builtin_bit_cast(int, v));
        return __builtin_bit_cast(float, r);
    }
}
template<int M>
__device__ __forceinline__ f32x2 lxor2(f32x2 z, int bp32) {
    f32x2 p; p.x = lxor<M>(z.x, bp32); p.y = lxor<M>(z.y, bp32); return p;
}

// ---- Rot gates; coefficients re-read from LDS (broadcast) to stay register-lean ----
template<int LM>
__device__ __forceinline__ void gate_local(St& s, const f32x2* u) {
    #pragma unroll
    for (int j0 = 0; j0 < NA; ++j0) {
        if (j0 & LM) continue;
        const int j1 = j0 | LM;
        f32x2 z0 = s.z[j0], z1 = s.z[j1];
        s.z[j0] = cmac(z1, u[2], u[3], cmul(z0, u[0], u[1]));
        s.z[j1] = cmac(z1, u[6], u[7], cmul(z0, u[4], u[5]));
    }
}
template<int M>
__device__ __forceinline__ void gate_lane(St& s, const f32x2* g, int bp32) {
    f32x2 ar = g[0], ai = g[1], br = g[2], bi = g[3];
    #pragma unroll
    for (int j = 0; j < NA; ++j) {
        f32x2 p = lxor2<M>(s.z[j], bp32);
        s.z[j] = cmac(p, br, bi, cmul(s.z[j], ar, ai));
    }
}

// ---- trips: swap j(2) with W-high / W-low bits (R9-validated addressing; one barrier) ----
__device__ __forceinline__ void trip_hi(St& s, int t, int wid, int lane, f32x2* ex) {
    #pragma unroll
    for (int j = 0; j < NA; ++j) ex[(j<<10) | t] = s.z[j];
    __syncthreads();
    const int base = ((wid>>2)<<10) | ((wid&3)<<6) | lane;
    #pragma unroll
    for (int j = 0; j < NA; ++j) s.z[j] = ex[base | (j<<8)];
}
__device__ __forceinline__ void trip_lo(St& s, int t, int wid, int lane, f32x2* ex) {
    #pragma unroll
    for (int j = 0; j < NA; ++j) ex[(j<<10) | t] = s.z[j];
    __syncthreads();
    const int base = ((wid&3)<<10) | ((wid>>2)<<8) | lane;
    #pragma unroll
    for (int j = 0; j < NA; ++j) s.z[j] = ex[base | (j<<6)];
}

__global__ __launch_bounds__(BT, 8)
void qnn_kernel(const float* __restrict__ x, const float* __restrict__ var,
                const float* __restrict__ hw, const float* __restrict__ hb,
                float* __restrict__ out)
{
    __shared__ f32x2 ex0[NA * BT];                  // 32 KiB
    __shared__ f32x2 ex1[NA * BT];                  // 32 KiB
    __shared__ f32x2 rotu[12][8];                   // layer-1 splats (local gates)
    __shared__ __align__(16) f32x2 rotg[6][2][4];   // lane-gate {ar,ai,br,bi} per bit
    __shared__ __align__(16) float fac[24][4];      // v_w[b] = {re,re,im,im}
    __shared__ float wavesum[16];

    const int t    = threadIdx.x;
    const int b    = blockIdx.x;
    const int lane = t & 63;
    const int wid  = t >> 6;            // 4 bits
    const int bp32 = (lane ^ 32) << 2;

    if (t < 12) {
        // layer-1 Rot for wire t
        const int g = 12 + t;
        const float phi   = var[g*3+0];
        const float theta = var[g*3+1];
        const float omega = var[g*3+2];
        float st, ct; sincosf(0.5f*theta, &st, &ct);
        float sp, cp; sincosf(-0.5f*(phi+omega), &sp, &cp);
        float sm, cm; sincosf(-0.5f*(phi-omega), &sm, &cm);
        const float v0r =  cp*ct, v0i =  sp*ct;   // u00
        const float v1r = -cm*st, v1i =  sm*st;   // u01
        const float v2r =  cm*st, v2i =  sm*st;   // u10
        const float v3r =  cp*ct, v3i = -sp*ct;   // u11
        rotu[t][0] = f32x2{v0r,v0r}; rotu[t][1] = f32x2{v0i,v0i};
        rotu[t][2] = f32x2{v1r,v1r}; rotu[t][3] = f32x2{v1i,v1i};
        rotu[t][4] = f32x2{v2r,v2r}; rotu[t][5] = f32x2{v2i,v2i};
        rotu[t][6] = f32x2{v3r,v3r}; rotu[t][7] = f32x2{v3i,v3i};
        if (t >= 2 && t < 8) {
            f32x2* g0 = rotg[t-2][0];  // bit=0: a=u00, b=u01
            g0[0] = f32x2{v0r,v0r}; g0[1] = f32x2{v0i,v0i};
            g0[2] = f32x2{v1r,v1r}; g0[3] = f32x2{v1i,v1i};
            f32x2* g1 = rotg[t-2][1];  // bit=1: a=u11, b=u10
            g1[0] = f32x2{v3r,v3r}; g1[1] = f32x2{v3i,v3i};
            g1[2] = f32x2{v2r,v2r}; g1[3] = f32x2{v2i,v2i};
        }
    } else if (t < 24) {
        // v_w = Rot^0_w * RY(x_w) |0>  (layer-0 product-state factor table)
        const int w = t - 12;
        const float phi   = var[w*3+0];
        const float theta = var[w*3+1];
        const float omega = var[w*3+2];
        float st, ct; sincosf(0.5f*theta, &st, &ct);
        float sp, cp; sincosf(-0.5f*(phi+omega), &sp, &cp);
        float sm, cm; sincosf(-0.5f*(phi-omega), &sm, &cm);
        float s_, c_; sincosf(0.5f * x[b*NW + w], &s_, &c_);
        const float v0r = cp*ct*c_ - cm*st*s_;
        const float v0i = sp*ct*c_ + sm*st*s_;
        const float v1r = cm*st*c_ + cp*ct*s_;
        const float v1i = sm*st*c_ - sp*ct*s_;
        fac[w*2+0][0] = v0r; fac[w*2+0][1] = v0r; fac[w*2+0][2] = v0i; fac[w*2+0][3] = v0i;
        fac[w*2+1][0] = v1r; fac[w*2+1][1] = v1r; fac[w*2+1][2] = v1i; fac[w*2+1][3] = v1i;
    }
    __syncthreads();

    // ---- construct psi1 = ring1 . (layer0 Rots) . RY |0> directly in L1' layout ----
    // L1' wires: 0<->j1 1<->j0 | 2..7 <-> l5..l0 | 8..11 <-> W3..W0
    // x = M1^-1 y: x0=j1^W0, x1=j0^j1^W0, x2=j0^l5, x3=l4^l5,...,x7=l0^l1,
    //              x8=W3^l0, x9=W2^W3, x10=W1^W2, x11=W0^W1
    St s;
    {
        const int l = lane, W = wid;
        auto ldf = [&](int w, int bit) -> f32x4 {
            return *reinterpret_cast<const f32x4*>(fac[(w << 1) | bit]);
        };
        const int b3  = ((l>>4)^(l>>5)) & 1;
        const int b4  = ((l>>3)^(l>>4)) & 1;
        const int b5  = ((l>>2)^(l>>3)) & 1;
        const int b6  = ((l>>1)^(l>>2)) & 1;
        const int b7  = ( l    ^(l>>1)) & 1;
        const int b8  = ((W>>3)^ l    ) & 1;
        const int b9  = ((W>>2)^(W>>3)) & 1;
        const int b10 = ((W>>1)^(W>>2)) & 1;
        const int b11 = ( W    ^(W>>1)) & 1;
        f32x4 f = ldf(3, b3);
        f32x2 P = f32x2{f.x, f.z};
        f = ldf(4,  b4);  P = cmul(P, f32x2{f.x,f.y}, f32x2{f.z,f.w});
        f = ldf(5,  b5);  P = cmul(P, f32x2{f.x,f.y}, f32x2{f.z,f.w});
        f = ldf(6,  b6);  P = cmul(P, f32x2{f.x,f.y}, f32x2{f.z,f.w});
        f = ldf(7,  b7);  P = cmul(P, f32x2{f.x,f.y}, f32x2{f.z,f.w});
        f = ldf(8,  b8);  P = cmul(P, f32x2{f.x,f.y}, f32x2{f.z,f.w});
        f = ldf(9,  b9);  P = cmul(P, f32x2{f.x,f.y}, f32x2{f.z,f.w});
        f = ldf(10, b10); P = cmul(P, f32x2{f.x,f.y}, f32x2{f.z,f.w});
        f = ldf(11, b11); P = cmul(P, f32x2{f.x,f.y}, f32x2{f.z,f.w});
        const int w0 = W & 1, l5 = (l >> 5) & 1;
        #pragma unroll
        for (int j = 0; j < NA; ++j) {
            const int j1 = (j >> 1) & 1, j0b = j & 1;
            f32x4 f0 = ldf(0, w0 ^ j1);
            f32x4 f1 = ldf(1, w0 ^ j1 ^ j0b);
            f32x4 f2 = ldf(2, l5 ^ j0b);
            f32x2 z = cmul(P, f32x2{f0.x,f0.y}, f32x2{f0.z,f0.w});
            z = cmul(z, f32x2{f1.x,f1.y}, f32x2{f1.z,f1.w});
            z = cmul(z, f32x2{f2.x,f2.y}, f32x2{f2.z,f2.w});
            s.z[j] = z;
        }
    }

    // ---- layer-1 Rot sweep ----
    gate_local<2>(s, rotu[0]);                        // wire0 (j1)
    gate_local<1>(s, rotu[1]);                        // wire1 (j0)
    gate_lane<32>(s, rotg[0][(lane>>5)&1], bp32);     // wire2
    gate_lane<16>(s, rotg[1][(lane>>4)&1], bp32);     // wire3
    gate_lane<8> (s, rotg[2][(lane>>3)&1], bp32);     // wire4
    gate_lane<4> (s, rotg[3][(lane>>2)&1], bp32);     // wire5
    gate_lane<2> (s, rotg[4][(lane>>1)&1], bp32);     // wire6
    gate_lane<1> (s, rotg[5][ lane    &1], bp32);     // wire7
    trip_hi(s, t, wid, lane, ex0);                    // j <-> W3W2 : wires 8,9 -> j
    gate_local<2>(s, rotu[8]);                        // wire8
    gate_local<1>(s, rotu[9]);                        // wire9
    trip_lo(s, t, wid, lane, ex1);                    // j <-> W1W0 : wires 10,11 -> j
    gate_local<2>(s, rotu[10]);                       // wire10
    gate_local<1>(s, rotu[11]);                       // wire11
    // ring r=2 fused into epilogue

    // ---- epilogue: probs -> z(M2 x) -> head ----
    // final layout: x0=W3 x1=W2 | x2..x7 = l5..l0 | x8=W1 x9=W0 | x10=j1 x11=j0
    float h[NW];
    #pragma unroll
    for (int w = 0; w < NW; ++w) h[w] = hw[w];
    const int l = lane, W = wid;
    const int y2 = ((l>>5) ^ (W>>3)) & 1;
    const int y3 = ((l>>4) ^ (W>>2)) & 1;
    const int y4 = ((l>>3) ^ (l>>5) ^ (W>>3)) & 1;
    const int y5 = ((l>>2) ^ (l>>4) ^ (W>>2)) & 1;
    const int y6 = ((l>>1) ^ (l>>3) ^ (l>>5) ^ (W>>3)) & 1;
    const int y7 = ( l     ^ (l>>2) ^ (l>>4) ^ (W>>2)) & 1;
    const int e0 = ((W>>1) ^ (l>>1) ^ (l>>3) ^ (l>>5)) & 1;   // y0 = j1 ^ e0
    const int y8 = e0 ^ ((W>>3) & 1);                          // y8; also e10
    const int o1 = ( W     ^  l     ^ (l>>2) ^ (l>>4)) & 1;   // y1 = j0 ^ o1
    const int y9 = o1 ^ ((W>>2) & 1);                          // y9; also o11

    const float base =
        (y2 ? -h[2] : h[2]) + (y3 ? -h[3] : h[3]) + (y4 ? -h[4] : h[4]) +
        (y5 ? -h[5] : h[5]) + (y6 ? -h[6] : h[6]) + (y7 ? -h[7] : h[7]) +
        (y8 ? -h[8] : h[8]) + (y9 ? -h[9] : h[9]);
    const float A = (e0 ? -h[0] : h[0]) + (y8 ? -h[10] : h[10]);   // * (-1)^j1
    const float B = (o1 ? -h[1] : h[1]) + (y9 ? -h[11] : h[11]);   // * (-1)^j0

    float acc = 0.0f;
    #pragma unroll
    for (int j = 0; j < NA; ++j) {
        const float pr = s.z[j].x*s.z[j].x + s.z[j].y*s.z[j].y;
        float zz = base;
        zz += (j & 2) ? -A : A;
        zz += (j & 1) ? -B : B;
        acc += pr * zz;
    }
    #pragma unroll
    for (int off = 32; off > 0; off >>= 1) acc += __shfl_down(acc, off, 64);
    if (lane == 0) wavesum[wid] = acc;
    __syncthreads();
    if (t == 0) {
        float r = hb[0];
        #pragma unroll
        for (int wv = 0; wv < 16; ++wv) r += wavesum[wv];
        out[b] = r;
    }
}

extern "C" void kernel_launch(void* const* d_in, const int* in_sizes, int n_in,
                              void* d_out, int out_size, void* d_ws, size_t ws_size,
                              hipStream_t stream) {
    const float* x   = (const float*)d_in[0];
    const float* var = (const float*)d_in[1];
    const float* hw  = (const float*)d_in[2];
    const float* hb  = (const float*)d_in[3];
    float* out = (float*)d_out;
    qnn_kernel<<<out_size, BT, 0, stream>>>(x, var, hw, hb, out);
}

// Round 13
// 14.430 us; speedup vs baseline: 1.0798x; 1.0798x over previous
//
#include <hip/hip_runtime.h>

constexpr int NW = 12;
constexpr int BT = 512;   // 1 sample/block; state bits [wid:3][lane:6][j:3]
constexpr int NA = 8;     // amps per thread

typedef float f32x2 __attribute__((ext_vector_type(2)));
typedef float f32x4 __attribute__((ext_vector_type(4)));

// ---- packed FP32 complex math (HW-validated R8-R12) ----
__device__ __forceinline__ f32x2 pkmul(f32x2 a, f32x2 b) {
    f32x2 d; asm("v_pk_mul_f32 %0, %1, %2" : "=v"(d) : "v"(a), "v"(b)); return d;
}
__device__ __forceinline__ f32x2 pkfma(f32x2 a, f32x2 b, f32x2 c) {
    f32x2 d; asm("v_pk_fma_f32 %0, %1, %2, %3" : "=v"(d) : "v"(a), "v"(b), "v"(c)); return d;
}
__device__ __forceinline__ f32x2 pkfma_swapneg(f32x2 a, f32x2 b, f32x2 c) {
    f32x2 d;
    asm("v_pk_fma_f32 %0, %1, %2, %3 op_sel:[1,0,0] op_sel_hi:[0,1,1] neg_lo:[1,0,0]"
        : "=v"(d) : "v"(a), "v"(b), "v"(c));
    return d;
}
__device__ __forceinline__ f32x2 cmul(f32x2 z, f32x2 ur, f32x2 ui) {
    return pkfma_swapneg(z, ui, pkmul(z, ur));
}
__device__ __forceinline__ f32x2 cmac(f32x2 z, f32x2 ur, f32x2 ui, f32x2 acc) {
    return pkfma_swapneg(z, ui, pkfma(z, ur, acc));
}

struct C2p { f32x2 r00,i00,r01,i01,r10,i10,r11,i11; };
struct St  { f32x2 z[NA]; };

// ---- cross-lane ----
template<int CTRL>
__device__ __forceinline__ float dppx(float v) {
    int r = __builtin_amdgcn_update_dpp(0, __builtin_bit_cast(int, v), CTRL, 0xF, 0xF, true);
    return __builtin_bit_cast(float, r);
}
// same-register permlane swap: rows exchange pairwise within the register ->
// exact lane-xor-16 / lane-xor-32, direction-convention-proof (R5 lesson).
__device__ __forceinline__ float permswap16(float v) {
    int r = __builtin_bit_cast(int, v);
    asm("v_permlane16_swap_b32 %0, %0" : "+v"(r));
    return __builtin_bit_cast(float, r);
}
__device__ __forceinline__ float permswap32(float v) {
    int r = __builtin_bit_cast(int, v);
    asm("v_permlane32_swap_b32 %0, %0" : "+v"(r));
    return __builtin_bit_cast(float, r);
}

// partner across lane-xor M. PL: use permlane swaps (VALU) for 16/32.
template<int M, bool PL>
__device__ __forceinline__ float lxor(float v, int bp32) {
    if constexpr (M == 1)      { return dppx<0xB1>(v); }
    else if constexpr (M == 2) { return dppx<0x4E>(v); }
    else if constexpr (M == 8) { return dppx<0x128>(v); }
    else if constexpr (M == 4) {
        int r = __builtin_amdgcn_ds_swizzle(__builtin_bit_cast(int, v), 0x101F);
        return __builtin_bit_cast(float, r);
    } else if constexpr (M == 16) {
        if constexpr (PL) return permswap16(v);
        else {
            int r = __builtin_amdgcn_ds_swizzle(__builtin_bit_cast(int, v), 0x401F);
            return __builtin_bit_cast(float, r);
        }
    } else {
        if constexpr (PL) return permswap32(v);
        else {
            int r = __builtin_amdgcn_ds_bpermute(bp32, __builtin_bit_cast(int, v));
            return __builtin_bit_cast(float, r);
        }
    }
}
template<int M, bool PL>
__device__ __forceinline__ f32x2 lxor2(f32x2 z, int bp32) {
    f32x2 p; p.x = lxor<M,PL>(z.x, bp32); p.y = lxor<M,PL>(z.y, bp32); return p;
}

// ---- Rot gates ----
template<int LM>
__device__ __forceinline__ void gate_local(St& s, const C2p& u) {
    #pragma unroll
    for (int j0 = 0; j0 < NA; ++j0) {
        if (j0 & LM) continue;
        const int j1 = j0 | LM;
        f32x2 z0 = s.z[j0], z1 = s.z[j1];
        s.z[j0] = cmac(z1, u.r01, u.i01, cmul(z0, u.r00, u.i00));
        s.z[j1] = cmac(z1, u.r11, u.i11, cmul(z0, u.r10, u.i10));
    }
}
template<int M, bool PL>
__device__ __forceinline__ void gate_lane(St& s, const C2p& u, int lane, int bp32) {
    const bool b = (lane & M) != 0;
    f32x2 ar = b ? u.r11 : u.r00, ai = b ? u.i11 : u.i00;
    f32x2 br = b ? u.r10 : u.r01, bi = b ? u.i10 : u.i01;
    #pragma unroll
    for (int j = 0; j < NA; ++j) {
        f32x2 p = lxor2<M,PL>(s.z[j], bp32);
        s.z[j] = cmac(p, br, bi, cmul(s.z[j], ar, ai));
    }
}

// ---- transpose: swap 3 wid bits with 3 j bits (one barrier; validated R7) ----
__device__ __forceinline__ void transpose_wl(St& s, int t, int wid, int lane, f32x2* ex) {
    #pragma unroll
    for (int j = 0; j < NA; ++j) ex[(j<<9) | t] = s.z[j];
    __syncthreads();
    #pragma unroll
    for (int j = 0; j < NA; ++j) s.z[j] = ex[(wid<<9) | (j<<6) | lane];
}

// ---- circuit (R11-validated structure): construct psi1 directly, layer-1 sweep, ----
// ---- ring2 fused in epilogue.                                                 ----
// L1 layout: y0..y2=j2,j1,j0 | y3..y8=l5..l0 | y9..y11=w2..w0
// x = M1^-1 y: x0=j2^w0  x1=j1^j2^w0  x2=j0^j1  x3=l5^j0  x4=l4^l5 ... x8=l0^l1
//              x9=w2^l0  x10=w1^w2  x11=w0^w1
template<bool PL>
__device__ __forceinline__ void circuit(St& s, f32x2* ex,
                                        const f32x2 (*rotu)[8],
                                        const float (*fac)[4],
                                        int t, int lane, int wid, int bp32) {
    const int l = lane, W = wid;
    auto ldf = [&](int w, int bit) -> f32x4 {
        return *reinterpret_cast<const f32x4*>(fac[(w << 1) | bit]);  // {re,re,im,im}
    };
    {
        const int b4  = ((l>>4) ^ (l>>5)) & 1;
        const int b5  = ((l>>3) ^ (l>>4)) & 1;
        const int b6  = ((l>>2) ^ (l>>3)) & 1;
        const int b7  = ((l>>1) ^ (l>>2)) & 1;
        const int b8  = ( l     ^ (l>>1)) & 1;
        const int b9  = ((W>>2) ^  l    ) & 1;
        const int b10 = ((W>>1) ^ (W>>2)) & 1;
        const int b11 = ( W     ^ (W>>1)) & 1;
        f32x4 f = ldf(4, b4);
        f32x2 P = f32x2{f.x, f.z};
        f = ldf(5,  b5);  P = cmul(P, f32x2{f.x,f.y}, f32x2{f.z,f.w});
        f = ldf(6,  b6);  P = cmul(P, f32x2{f.x,f.y}, f32x2{f.z,f.w});
        f = ldf(7,  b7);  P = cmul(P, f32x2{f.x,f.y}, f32x2{f.z,f.w});
        f = ldf(8,  b8);  P = cmul(P, f32x2{f.x,f.y}, f32x2{f.z,f.w});
        f = ldf(9,  b9);  P = cmul(P, f32x2{f.x,f.y}, f32x2{f.z,f.w});
        f = ldf(10, b10); P = cmul(P, f32x2{f.x,f.y}, f32x2{f.z,f.w});
        f = ldf(11, b11); P = cmul(P, f32x2{f.x,f.y}, f32x2{f.z,f.w});
        const int w0 = W & 1, l5 = (l >> 5) & 1;
        f32x4 v0a = ldf(0, w0),  v0b = ldf(0, w0 ^ 1);   // index j2
        f32x4 v1a = ldf(1, w0),  v1b = ldf(1, w0 ^ 1);   // index j1^j2
        f32x4 v2a = ldf(2, 0),   v2b = ldf(2, 1);        // index j0^j1
        f32x4 v3a = ldf(3, l5),  v3b = ldf(3, l5 ^ 1);   // index j0
        #pragma unroll
        for (int j = 0; j < NA; ++j) {
            const int a0 = (j >> 2) & 1;
            const int a1 = ((j >> 1) ^ (j >> 2)) & 1;
            const int a2 = (j ^ (j >> 1)) & 1;
            const int a3 = j & 1;
            const f32x4 g0 = a0 ? v0b : v0a;   // compile-time selects
            const f32x4 g1 = a1 ? v1b : v1a;
            const f32x4 g2 = a2 ? v2b : v2a;
            const f32x4 g3 = a3 ? v3b : v3a;
            f32x2 z = cmul(P, f32x2{g0.x,g0.y}, f32x2{g0.z,g0.w});
            z = cmul(z, f32x2{g1.x,g1.y}, f32x2{g1.z,g1.w});
            z = cmul(z, f32x2{g2.x,g2.y}, f32x2{g2.z,g2.w});
            z = cmul(z, f32x2{g3.x,g3.y}, f32x2{g3.z,g3.w});
            s.z[j] = z;
        }
    }
    // ===== layer 1 Rot sweep (L1) =====
    auto ld = [&](int g) -> C2p {
        C2p u;
        u.r00 = rotu[g][0]; u.i00 = rotu[g][1];
        u.r01 = rotu[g][2]; u.i01 = rotu[g][3];
        u.r10 = rotu[g][4]; u.i10 = rotu[g][5];
        u.r11 = rotu[g][6]; u.i11 = rotu[g][7];
        return u;
    };
    { C2p u = ld(0);  gate_local<4>(s, u); }               // wire0
    { C2p u = ld(1);  gate_local<2>(s, u); }               // wire1
    { C2p u = ld(2);  gate_local<1>(s, u); }               // wire2
    { C2p u = ld(3);  gate_lane<32,PL>(s, u, lane, bp32); }
    { C2p u = ld(4);  gate_lane<16,PL>(s, u, lane, bp32); }
    { C2p u = ld(5);  gate_lane<8,PL >(s, u, lane, bp32); }
    { C2p u = ld(6);  gate_lane<4,PL >(s, u, lane, bp32); }
    { C2p u = ld(7);  gate_lane<2,PL >(s, u, lane, bp32); }
    { C2p u = ld(8);  gate_lane<1,PL >(s, u, lane, bp32); }
    transpose_wl(s, t, wid, lane, ex);                     // -> L0
    { C2p u = ld(9);  gate_local<4>(s, u); }               // wire9
    { C2p u = ld(10); gate_local<2>(s, u); }
    { C2p u = ld(11); gate_local<1>(s, u); }
}

__global__ __launch_bounds__(BT)
void qnn_kernel(const float* __restrict__ x, const float* __restrict__ var,
                const float* __restrict__ hw, const float* __restrict__ hb,
                float* __restrict__ out)
{
    __shared__ f32x2 ex[NA * BT];              // 32 KiB
    __shared__ f32x2 rotu[12][8];              // layer-1 splat matrices
    __shared__ __align__(16) float fac[24][4]; // v_w[b] = {re,re,im,im}
    __shared__ float wavesum[8];

    const int t    = threadIdx.x;
    const int b    = blockIdx.x;
    const int lane = t & 63;
    const int wid  = t >> 6;
    const int bp32 = (lane ^ 32) << 2;

    // permlane same-register semantics self-check (wave-uniform)
    bool pl_ok;
    {
        float lv = __builtin_bit_cast(float, lane);
        int r16 = __builtin_bit_cast(int, permswap16(lv));
        int r32 = __builtin_bit_cast(int, permswap32(lv));
        pl_ok = __all((r16 == (lane ^ 16)) && (r32 == (lane ^ 32)));
    }

    if (t < 12) {
        // layer-1 Rot matrix for wire t, splatted
        const int g = 12 + t;
        const float phi   = var[g*3+0];
        const float theta = var[g*3+1];
        const float omega = var[g*3+2];
        float st, ct; sincosf(0.5f*theta, &st, &ct);
        float sp, cp; sincosf(-0.5f*(phi+omega), &sp, &cp);
        float sm, cm; sincosf(-0.5f*(phi-omega), &sm, &cm);
        const float v0r =  cp*ct, v0i =  sp*ct;
        const float v1r = -cm*st, v1i =  sm*st;
        const float v2r =  cm*st, v2i =  sm*st;
        const float v3r =  cp*ct, v3i = -sp*ct;
        rotu[t][0] = f32x2{v0r, v0r}; rotu[t][1] = f32x2{v0i, v0i};
        rotu[t][2] = f32x2{v1r, v1r}; rotu[t][3] = f32x2{v1i, v1i};
        rotu[t][4] = f32x2{v2r, v2r}; rotu[t][5] = f32x2{v2i, v2i};
        rotu[t][6] = f32x2{v3r, v3r}; rotu[t][7] = f32x2{v3i, v3i};
    } else if (t < 24) {
        // v_w = Rot^0_w * RY(x_w) |0> for wire w (product-state factor table)
        const int w = t - 12;
        const float phi   = var[w*3+0];
        const float theta = var[w*3+1];
        const float omega = var[w*3+2];
        float st, ct; sincosf(0.5f*theta, &st, &ct);
        float sp, cp; sincosf(-0.5f*(phi+omega), &sp, &cp);
        float sm, cm; sincosf(-0.5f*(phi-omega), &sm, &cm);
        float s_, c_; sincosf(0.5f * x[b*NW + w], &s_, &c_);
        const float v0r = cp*ct*c_ - cm*st*s_;
        const float v0i = sp*ct*c_ + sm*st*s_;
        const float v1r = cm*st*c_ + cp*ct*s_;
        const float v1i = sm*st*c_ - sp*ct*s_;
        fac[w*2+0][0] = v0r; fac[w*2+0][1] = v0r; fac[w*2+0][2] = v0i; fac[w*2+0][3] = v0i;
        fac[w*2+1][0] = v1r; fac[w*2+1][1] = v1r; fac[w*2+1][2] = v1i; fac[w*2+1][3] = v1i;
    }
    __syncthreads();

    St s;
    if (pl_ok) circuit<true >(s, ex, rotu, fac, t, lane, wid, bp32);
    else       circuit<false>(s, ex, rotu, fac, t, lane, wid, bp32);

    // ---- epilogue: probs -> z(M2 x) -> head (ring r=2 fused; validated R10/R11) ----
    // L0: x0=W2 x1=W1 x2=W0 | x3..x8 = l5..l0 | x9=j2 x10=j1 x11=j0
    float h[NW];
    #pragma unroll
    for (int w = 0; w < NW; ++w) h[w] = hw[w];
    const int W = wid, l = lane;
    const int s2 = ((W >> 2) ^ W) & 1;
    const int s3 = ((W >> 1) ^ (l >> 5)) & 1;
    const int s4 = s2 ^ ((l >> 4) & 1);
    const int s5 = s3 ^ ((l >> 3) & 1);
    const int s6 = s4 ^ ((l >> 2) & 1);
    const int s7 = s5 ^ ((l >> 1) & 1);
    const int s8 = s6 ^ (l & 1);
    const int c0 = (W ^ (l >> 4) ^ (l >> 2) ^ l) & 1;
    const int c10 = c0 ^ ((W >> 2) & 1);
    const int c9 = ((W >> 1) ^ (l >> 5) ^ (l >> 3) ^ (l >> 1)) & 1;
    const int c1 = c9 ^ ((W >> 1) & 1);

    const float base =
        (s2 ? -h[2] : h[2]) + (s3 ? -h[3] : h[3]) + (s4 ? -h[4] : h[4]) +
        (s5 ? -h[5] : h[5]) + (s6 ? -h[6] : h[6]) + (s7 ? -h[7] : h[7]) +
        (s8 ? -h[8] : h[8]);
    const float A  = (c0 ? -h[0] : h[0]) + (c10 ? -h[10] : h[10]);   // * (-1)^j1
    const float B  = (c1 ? -h[1] : h[1]) + (c9  ? -h[11] : h[11]);   // * (-1)^(j2^j0)
    const float Cc = (c9 ? -h[9] : h[9]);                            // * (-1)^j2

    float acc = 0.0f;
    #pragma unroll
    for (int j = 0; j < NA; ++j) {
        const float pr = s.z[j].x*s.z[j].x + s.z[j].y*s.z[j].y;
        float zz = base;
        zz += (j & 2) ? -A : A;
        zz += (j & 4) ? -Cc : Cc;
        zz += (((j >> 2) ^ j) & 1) ? -B : B;
        acc += pr * zz;
    }
    #pragma unroll
    for (int off = 32; off > 0; off >>= 1) acc += __shfl_down(acc, off, 64);
    if (lane == 0) wavesum[wid] = acc;
    __syncthreads();
    if (t == 0) {
        float r = hb[0];
        #pragma unroll
        for (int wv = 0; wv < 8; ++wv) r += wavesum[wv];
        out[b] = r;
    }
}

extern "C" void kernel_launch(void* const* d_in, const int* in_sizes, int n_in,
                              void* d_out, int out_size, void* d_ws, size_t ws_size,
                              hipStream_t stream) {
    const float* x   = (const float*)d_in[0];
    const float* var = (const float*)d_in[1];
    const float* hw  = (const float*)d_in[2];
    const float* hb  = (const float*)d_in[3];
    float* out = (float*)d_out;
    qnn_kernel<<<out_size, BT, 0, stream>>>(x, var, hw, hb, out);
}

// Round 14
// 13.194 us; speedup vs baseline: 1.1810x; 1.0937x over previous
//
#include <hip/hip_runtime.h>

constexpr int NW = 12;
constexpr int BT = 512;   // 1 sample/block; state bits [wid:3][lane:6][j:3]
constexpr int NA = 8;     // amps per thread

typedef float f32x2 __attribute__((ext_vector_type(2)));
typedef float f32x4 __attribute__((ext_vector_type(4)));

// ---- packed FP32 complex math (HW-validated R8-R13) ----
__device__ __forceinline__ f32x2 pkmul(f32x2 a, f32x2 b) {
    f32x2 d; asm("v_pk_mul_f32 %0, %1, %2" : "=v"(d) : "v"(a), "v"(b)); return d;
}
__device__ __forceinline__ f32x2 pkfma(f32x2 a, f32x2 b, f32x2 c) {
    f32x2 d; asm("v_pk_fma_f32 %0, %1, %2, %3" : "=v"(d) : "v"(a), "v"(b), "v"(c)); return d;
}
__device__ __forceinline__ f32x2 pkfma_swapneg(f32x2 a, f32x2 b, f32x2 c) {
    f32x2 d;
    asm("v_pk_fma_f32 %0, %1, %2, %3 op_sel:[1,0,0] op_sel_hi:[0,1,1] neg_lo:[1,0,0]"
        : "=v"(d) : "v"(a), "v"(b), "v"(c));
    return d;
}
__device__ __forceinline__ f32x2 cmul(f32x2 z, f32x2 ur, f32x2 ui) {
    return pkfma_swapneg(z, ui, pkmul(z, ur));
}
__device__ __forceinline__ f32x2 cmac(f32x2 z, f32x2 ur, f32x2 ui, f32x2 acc) {
    return pkfma_swapneg(z, ui, pkfma(z, ur, acc));
}
// packed{re,im} x packed{re,im} complex product
__device__ __forceinline__ f32x2 cpmul(f32x2 a, f32x2 b) {
    return f32x2{a.x*b.x - a.y*b.y, a.x*b.y + a.y*b.x};
}

struct C2p { f32x2 r00,i00,r01,i01,r10,i10,r11,i11; };
struct St  { f32x2 z[NA]; };

// ---- cross-lane ----
template<int CTRL>
__device__ __forceinline__ float dppx(float v) {
    int r = __builtin_amdgcn_update_dpp(0, __builtin_bit_cast(int, v), CTRL, 0xF, 0xF, true);
    return __builtin_bit_cast(float, r);
}
__device__ __forceinline__ float permswap16(float v) {
    int r = __builtin_bit_cast(int, v);
    asm("v_permlane16_swap_b32 %0, %0" : "+v"(r));
    return __builtin_bit_cast(float, r);
}
__device__ __forceinline__ float permswap32(float v) {
    int r = __builtin_bit_cast(int, v);
    asm("v_permlane32_swap_b32 %0, %0" : "+v"(r));
    return __builtin_bit_cast(float, r);
}

// partner across lane-xor M. FAST: VALU-pipe variants for 4/16/32 (self-checked).
template<int M, bool FAST>
__device__ __forceinline__ float lxor(float v, int bp32) {
    if constexpr (M == 1)      { return dppx<0xB1>(v); }     // quad_perm [1,0,3,2]
    else if constexpr (M == 2) { return dppx<0x4E>(v); }     // quad_perm [2,3,0,1]
    else if constexpr (M == 8) { return dppx<0x128>(v); }    // row_ror:8
    else if constexpr (M == 4) {
        if constexpr (FAST) return dppx<0x1B>(dppx<0x141>(v));  // xor7 then xor3 = xor4
        else {
            int r = __builtin_amdgcn_ds_swizzle(__builtin_bit_cast(int, v), 0x101F);
            return __builtin_bit_cast(float, r);
        }
    } else if constexpr (M == 16) {
        if constexpr (FAST) return permswap16(v);
        else {
            int r = __builtin_amdgcn_ds_swizzle(__builtin_bit_cast(int, v), 0x401F);
            return __builtin_bit_cast(float, r);
        }
    } else {
        if constexpr (FAST) return permswap32(v);
        else {
            int r = __builtin_amdgcn_ds_bpermute(bp32, __builtin_bit_cast(int, v));
            return __builtin_bit_cast(float, r);
        }
    }
}
template<int M, bool FAST>
__device__ __forceinline__ f32x2 lxor2(f32x2 z, int bp32) {
    f32x2 p; p.x = lxor<M,FAST>(z.x, bp32); p.y = lxor<M,FAST>(z.y, bp32); return p;
}

// ---- Rot gates ----
template<int LM>
__device__ __forceinline__ void gate_local(St& s, const C2p& u) {
    #pragma unroll
    for (int j0 = 0; j0 < NA; ++j0) {
        if (j0 & LM) continue;
        const int j1 = j0 | LM;
        f32x2 z0 = s.z[j0], z1 = s.z[j1];
        s.z[j0] = cmac(z1, u.r01, u.i01, cmul(z0, u.r00, u.i00));
        s.z[j1] = cmac(z1, u.r11, u.i11, cmul(z0, u.r10, u.i10));
    }
}
// lane gate: coefficients pre-selected by lane bit (4 f32x2: ar,ai,br,bi)
template<int M, bool FAST>
__device__ __forceinline__ void gate_lane(St& s, const f32x2* g, int bp32) {
    f32x2 ar = g[0], ai = g[1], br = g[2], bi = g[3];
    #pragma unroll
    for (int j = 0; j < NA; ++j) {
        f32x2 p = lxor2<M,FAST>(s.z[j], bp32);
        s.z[j] = cmac(p, br, bi, cmul(s.z[j], ar, ai));
    }
}

// ---- transpose: swap 3 wid bits with 3 j bits (one barrier; validated R7) ----
__device__ __forceinline__ void transpose_wl(St& s, int t, int wid, int lane, f32x2* ex) {
    #pragma unroll
    for (int j = 0; j < NA; ++j) ex[(j<<9) | t] = s.z[j];
    __syncthreads();
    #pragma unroll
    for (int j = 0; j < NA; ++j) s.z[j] = ex[(wid<<9) | (j<<6) | lane];
}

// ---- circuit (R11-validated structure) ----
// L1 layout: y0..y2=j2,j1,j0 | y3..y8=l5..l0 | y9..y11=w2..w0
// x = M1^-1 y: x0=j2^w0  x1=j1^j2^w0  x2=j0^j1  x3=l5^j0  x4=l4^l5 ... x8=l0^l1
//              x9=w2^l0  x10=w1^w2  x11=w0^w1
template<bool FAST>
__device__ __forceinline__ void circuit(St& s, f32x2* ex,
                                        const f32x2 (*rotu)[8],
                                        const f32x2 (*rotg)[2][4],
                                        const float (*fac)[4],
                                        int t, int lane, int wid, int bp32) {
    const int l = lane, W = wid;
    auto ldf = [&](int w, int bit) -> f32x4 {
        return *reinterpret_cast<const f32x4*>(fac[(w << 1) | bit]);  // {re,re,im,im}
    };
    {
        const int b4  = ((l>>4) ^ (l>>5)) & 1;
        const int b5  = ((l>>3) ^ (l>>4)) & 1;
        const int b6  = ((l>>2) ^ (l>>3)) & 1;
        const int b7  = ((l>>1) ^ (l>>2)) & 1;
        const int b8  = ( l     ^ (l>>1)) & 1;
        const int b9  = ((W>>2) ^  l    ) & 1;
        const int b10 = ((W>>1) ^ (W>>2)) & 1;
        const int b11 = ( W     ^ (W>>1)) & 1;
        // tree-structured prefix: 3 parallel chains + 2 packed-packed muls
        f32x4 f4 = ldf(4,b4), f5 = ldf(5,b5), f6 = ldf(6,b6), f7 = ldf(7,b7);
        f32x4 f8 = ldf(8,b8), f9 = ldf(9,b9), fA = ldf(10,b10), fB = ldf(11,b11);
        f32x2 cA = cmul(f32x2{f4.x,f4.z}, f32x2{f5.x,f5.y}, f32x2{f5.z,f5.w});
        cA = cmul(cA, f32x2{f6.x,f6.y}, f32x2{f6.z,f6.w});
        f32x2 cB = cmul(f32x2{f7.x,f7.z}, f32x2{f8.x,f8.y}, f32x2{f8.z,f8.w});
        cB = cmul(cB, f32x2{f9.x,f9.y}, f32x2{f9.z,f9.w});
        f32x2 cC = cmul(f32x2{fA.x,fA.z}, f32x2{fB.x,fB.y}, f32x2{fB.z,fB.w});
        f32x2 P = cpmul(cpmul(cA, cB), cC);
        const int w0 = W & 1, l5 = (l >> 5) & 1;
        f32x4 v0a = ldf(0, w0),  v0b = ldf(0, w0 ^ 1);   // index j2
        f32x4 v1a = ldf(1, w0),  v1b = ldf(1, w0 ^ 1);   // index j1^j2
        f32x4 v2a = ldf(2, 0),   v2b = ldf(2, 1);        // index j0^j1
        f32x4 v3a = ldf(3, l5),  v3b = ldf(3, l5 ^ 1);   // index j0
        #pragma unroll
        for (int j = 0; j < NA; ++j) {
            const int a0 = (j >> 2) & 1;
            const int a1 = ((j >> 1) ^ (j >> 2)) & 1;
            const int a2 = (j ^ (j >> 1)) & 1;
            const int a3 = j & 1;
            const f32x4 g0 = a0 ? v0b : v0a;   // compile-time selects
            const f32x4 g1 = a1 ? v1b : v1a;
            const f32x4 g2 = a2 ? v2b : v2a;
            const f32x4 g3 = a3 ? v3b : v3a;
            f32x2 z = cmul(P, f32x2{g0.x,g0.y}, f32x2{g0.z,g0.w});
            z = cmul(z, f32x2{g1.x,g1.y}, f32x2{g1.z,g1.w});
            z = cmul(z, f32x2{g2.x,g2.y}, f32x2{g2.z,g2.w});
            z = cmul(z, f32x2{g3.x,g3.y}, f32x2{g3.z,g3.w});
            s.z[j] = z;
        }
    }
    // ===== layer 1 Rot sweep (L1) =====
    auto ld = [&](int g) -> C2p {
        C2p u;
        u.r00 = rotu[g][0]; u.i00 = rotu[g][1];
        u.r01 = rotu[g][2]; u.i01 = rotu[g][3];
        u.r10 = rotu[g][4]; u.i10 = rotu[g][5];
        u.r11 = rotu[g][6]; u.i11 = rotu[g][7];
        return u;
    };
    { C2p u = ld(0);  gate_local<4>(s, u); }               // wire0
    { C2p u = ld(1);  gate_local<2>(s, u); }               // wire1
    { C2p u = ld(2);  gate_local<1>(s, u); }               // wire2
    gate_lane<32,FAST>(s, rotg[0][(lane>>5)&1], bp32);     // wire3
    gate_lane<16,FAST>(s, rotg[1][(lane>>4)&1], bp32);     // wire4
    gate_lane<8,FAST >(s, rotg[2][(lane>>3)&1], bp32);     // wire5
    gate_lane<4,FAST >(s, rotg[3][(lane>>2)&1], bp32);     // wire6
    gate_lane<2,FAST >(s, rotg[4][(lane>>1)&1], bp32);     // wire7
    gate_lane<1,FAST >(s, rotg[5][ lane    &1], bp32);     // wire8
    transpose_wl(s, t, wid, lane, ex);                     // -> L0
    { C2p u = ld(9);  gate_local<4>(s, u); }               // wire9
    { C2p u = ld(10); gate_local<2>(s, u); }
    { C2p u = ld(11); gate_local<1>(s, u); }
}

__global__ __launch_bounds__(BT)
void qnn_kernel(const float* __restrict__ x, const float* __restrict__ var,
                const float* __restrict__ hw, const float* __restrict__ hb,
                float* __restrict__ out)
{
    __shared__ f32x2 ex[NA * BT];                  // 32 KiB
    __shared__ f32x2 rotu[12][8];                  // layer-1 splat matrices (local gates)
    __shared__ __align__(16) f32x2 rotg[6][2][4];  // lane-gate pre-selected {ar,ai,br,bi}
    __shared__ __align__(16) float fac[24][4];     // v_w[b] = {re,re,im,im}
    __shared__ float wavesum[8];

    const int t    = threadIdx.x;
    const int b    = blockIdx.x;
    const int lane = t & 63;
    const int wid  = t >> 6;
    const int bp32 = (lane ^ 32) << 2;

    // VALU cross-lane semantics self-check (wave-uniform; fallback = validated DS path)
    bool fast_ok;
    {
        float lv = __builtin_bit_cast(float, lane);
        int r16 = __builtin_bit_cast(int, permswap16(lv));
        int r32 = __builtin_bit_cast(int, permswap32(lv));
        int r4  = __builtin_bit_cast(int, dppx<0x1B>(dppx<0x141>(lv)));
        fast_ok = __all((r16 == (lane ^ 16)) && (r32 == (lane ^ 32)) && (r4 == (lane ^ 4)));
    }

    if (wid == 0 && lane < 12) {
        // layer-1 Rot matrix for wire `lane`, splatted (+ lane-gate table for wires 3-8)
        const int w = lane;
        const int g = 12 + w;
        const float phi   = var[g*3+0];
        const float theta = var[g*3+1];
        const float omega = var[g*3+2];
        float st, ct; sincosf(0.5f*theta, &st, &ct);
        float sp, cp; sincosf(-0.5f*(phi+omega), &sp, &cp);
        float sm, cm; sincosf(-0.5f*(phi-omega), &sm, &cm);
        const float v0r =  cp*ct, v0i =  sp*ct;   // u00
        const float v1r = -cm*st, v1i =  sm*st;   // u01
        const float v2r =  cm*st, v2i =  sm*st;   // u10
        const float v3r =  cp*ct, v3i = -sp*ct;   // u11
        rotu[w][0] = f32x2{v0r,v0r}; rotu[w][1] = f32x2{v0i,v0i};
        rotu[w][2] = f32x2{v1r,v1r}; rotu[w][3] = f32x2{v1i,v1i};
        rotu[w][4] = f32x2{v2r,v2r}; rotu[w][5] = f32x2{v2i,v2i};
        rotu[w][6] = f32x2{v3r,v3r}; rotu[w][7] = f32x2{v3i,v3i};
        if (w >= 3 && w < 9) {
            f32x2* g0 = rotg[w-3][0];   // bit=0: a=u00, b=u01
            g0[0] = f32x2{v0r,v0r}; g0[1] = f32x2{v0i,v0i};
            g0[2] = f32x2{v1r,v1r}; g0[3] = f32x2{v1i,v1i};
            f32x2* g1 = rotg[w-3][1];   // bit=1: a=u11, b=u10
            g1[0] = f32x2{v3r,v3r}; g1[1] = f32x2{v3i,v3i};
            g1[2] = f32x2{v2r,v2r}; g1[3] = f32x2{v2i,v2i};
        }
    } else if (wid == 1 && lane < 12) {
        // v_w = Rot^0_w * RY(x_w)|0>  (layer-0 product factor table) — parallel wave
        const int w = lane;
        const float phi   = var[w*3+0];
        const float theta = var[w*3+1];
        const float omega = var[w*3+2];
        float st, ct; sincosf(0.5f*theta, &st, &ct);
        float sp, cp; sincosf(-0.5f*(phi+omega), &sp, &cp);
        float sm, cm; sincosf(-0.5f*(phi-omega), &sm, &cm);
        float s_, c_; sincosf(0.5f * x[b*NW + w], &s_, &c_);
        const float v0r = cp*ct*c_ - cm*st*s_;
        const float v0i = sp*ct*c_ + sm*st*s_;
        const float v1r = cm*st*c_ + cp*ct*s_;
        const float v1i = sm*st*c_ - sp*ct*s_;
        fac[w*2+0][0] = v0r; fac[w*2+0][1] = v0r; fac[w*2+0][2] = v0i; fac[w*2+0][3] = v0i;
        fac[w*2+1][0] = v1r; fac[w*2+1][1] = v1r; fac[w*2+1][2] = v1i; fac[w*2+1][3] = v1i;
    }
    __syncthreads();

    St s;
    if (fast_ok) circuit<true >(s, ex, rotu, rotg, fac, t, lane, wid, bp32);
    else         circuit<false>(s, ex, rotu, rotg, fac, t, lane, wid, bp32);

    // ---- epilogue: probs -> z(M2 x) -> head (ring r=2 fused; validated R10/R11) ----
    // L0: x0=W2 x1=W1 x2=W0 | x3..x8 = l5..l0 | x9=j2 x10=j1 x11=j0
    float h[NW];
    #pragma unroll
    for (int w = 0; w < NW; ++w) h[w] = hw[w];
    const int W = wid, l = lane;
    const int s2 = ((W >> 2) ^ W) & 1;
    const int s3 = ((W >> 1) ^ (l >> 5)) & 1;
    const int s4 = s2 ^ ((l >> 4) & 1);
    const int s5 = s3 ^ ((l >> 3) & 1);
    const int s6 = s4 ^ ((l >> 2) & 1);
    const int s7 = s5 ^ ((l >> 1) & 1);
    const int s8 = s6 ^ (l & 1);
    const int c0 = (W ^ (l >> 4) ^ (l >> 2) ^ l) & 1;
    const int c10 = c0 ^ ((W >> 2) & 1);
    const int c9 = ((W >> 1) ^ (l >> 5) ^ (l >> 3) ^ (l >> 1)) & 1;
    const int c1 = c9 ^ ((W >> 1) & 1);

    const float base =
        (s2 ? -h[2] : h[2]) + (s3 ? -h[3] : h[3]) + (s4 ? -h[4] : h[4]) +
        (s5 ? -h[5] : h[5]) + (s6 ? -h[6] : h[6]) + (s7 ? -h[7] : h[7]) +
        (s8 ? -h[8] : h[8]);
    const float A  = (c0 ? -h[0] : h[0]) + (c10 ? -h[10] : h[10]);   // * (-1)^j1
    const float B  = (c1 ? -h[1] : h[1]) + (c9  ? -h[11] : h[11]);   // * (-1)^(j2^j0)
    const float Cc = (c9 ? -h[9] : h[9]);                            // * (-1)^j2

    float acc = 0.0f;
    #pragma unroll
    for (int j = 0; j < NA; ++j) {
        const float pr = s.z[j].x*s.z[j].x + s.z[j].y*s.z[j].y;
        float zz = base;
        zz += (j & 2) ? -A : A;
        zz += (j & 4) ? -Cc : Cc;
        zz += (((j >> 2) ^ j) & 1) ? -B : B;
        acc += pr * zz;
    }
    #pragma unroll
    for (int off = 32; off > 0; off >>= 1) acc += __shfl_down(acc, off, 64);
    if (lane == 0) wavesum[wid] = acc;
    __syncthreads();
    if (t == 0) {
        float r = hb[0];
        #pragma unroll
        for (int wv = 0; wv < 8; ++wv) r += wavesum[wv];
        out[b] = r;
    }
}

extern "C" void kernel_launch(void* const* d_in, const int* in_sizes, int n_in,
                              void* d_out, int out_size, void* d_ws, size_t ws_size,
                              hipStream_t stream) {
    const float* x   = (const float*)d_in[0];
    const float* var = (const float*)d_in[1];
    const float* hw  = (const float*)d_in[2];
    const float* hb  = (const float*)d_in[3];
    float* out = (float*)d_out;
    qnn_kernel<<<out_size, BT, 0, stream>>>(x, var, hw, hb, out);
}